// Round 15
// baseline (358.688 us; speedup 1.0000x reference)
//
#include <hip/hip_runtime.h>
#include <math.h>

#define HDIM 256
#define NSTATE 64
#define NDEPTH 4
#define LSEQ 2048
#define NBATCH 8
#define NROWS (NBATCH*LSEQ)   // 16384
#define HN (HDIM*NSTATE)      // 16384
#define INDIM 51
#define OUTC 204
#define M1 (256*4096)         // shorts per variant (256 h x 64x64)
#define GPAD 40               // padded k-stride (shorts) for B tiles
#define LPAD 74               // padded l-stride (shorts) for z^T tiles (bank-spread)

typedef short bfrag8 __attribute__((ext_vector_type(8)));
typedef float facc4 __attribute__((ext_vector_type(4)));

// ---------------- helpers ----------------
template<int CTRL>
__device__ __forceinline__ float dpp_add(float x) {
  int y = __builtin_amdgcn_update_dpp(0, __float_as_int(x), CTRL, 0xf, 0xf, true);
  return x + __int_as_float(y);
}
__device__ __forceinline__ float wave_sum64(float x) {
  x = dpp_add<0x111>(x);
  x = dpp_add<0x112>(x);
  x = dpp_add<0x114>(x);
  x = dpp_add<0x118>(x);
  x = dpp_add<0x142>(x);
  x = dpp_add<0x143>(x);
  return x;   // total in lane 63
}
__device__ __forceinline__ float rdlane(float v, int lane) {
  return __int_as_float(__builtin_amdgcn_readlane(__float_as_int(v), lane));
}
__device__ __forceinline__ float gelu_tanh(float x) {
  float x3 = x*x*x;
  return 0.5f*x*(1.f + tanhf(0.7978845608028654f*(x + 0.044715f*x3)));
}
__device__ __forceinline__ unsigned short f2bf(float x) {
  unsigned u = __float_as_uint(x);
  unsigned r = (u + 0x7FFFu + ((u >> 16) & 1u)) >> 16;
  return (unsigned short)r;
}
__device__ __forceinline__ float bf2f(unsigned short h) {
  return __uint_as_float(((unsigned)h) << 16);
}
__device__ __forceinline__ bfrag8 mk8(unsigned a, unsigned b, unsigned c, unsigned d) {
  union { unsigned u[4]; bfrag8 f; } U;
  U.u[0]=a; U.u[1]=b; U.u[2]=c; U.u[3]=d; return U.f;
}
__device__ __forceinline__ unsigned long long pk4(unsigned short a,unsigned short b,
                                                  unsigned short c,unsigned short d){
  return (unsigned long long)a | ((unsigned long long)b<<16) |
         ((unsigned long long)c<<32) | ((unsigned long long)d<<48);
}

// ---------------- input projection: x[16384,51] @ w[51,256] + b -> u fp32 + uth/utl splits
__global__ __launch_bounds__(256) void proj_kernel(
    const float* __restrict__ x, const float* __restrict__ w,
    const float* __restrict__ bias, float* __restrict__ u,
    unsigned short* __restrict__ uth, unsigned short* __restrict__ utl) {
  __shared__ float xs[8][52];
  const int r0 = blockIdx.x * 8;
  const int tid = threadIdx.x;
  for (int idx = tid; idx < 8*INDIM; idx += 256) {
    int rr = idx / INDIM, k = idx % INDIM;
    xs[rr][k] = x[(size_t)(r0+rr)*INDIM + k];
  }
  __syncthreads();
  const int hcol = tid;
  float acc[8];
  const float bb = bias[hcol];
#pragma unroll
  for (int rr = 0; rr < 8; ++rr) acc[rr] = bb;
#pragma unroll
  for (int k = 0; k < 48; k += 4) {
    float w0 = w[(k+0)*HDIM + hcol];
    float w1 = w[(k+1)*HDIM + hcol];
    float w2 = w[(k+2)*HDIM + hcol];
    float w3 = w[(k+3)*HDIM + hcol];
#pragma unroll
    for (int rr = 0; rr < 8; ++rr) {
      float4 xv = *(const float4*)&xs[rr][k];
      acc[rr] = fmaf(xv.x, w0, acc[rr]);
      acc[rr] = fmaf(xv.y, w1, acc[rr]);
      acc[rr] = fmaf(xv.z, w2, acc[rr]);
      acc[rr] = fmaf(xv.w, w3, acc[rr]);
    }
  }
#pragma unroll
  for (int k = 48; k < INDIM; ++k) {
    float wk = w[k*HDIM + hcol];
#pragma unroll
    for (int rr = 0; rr < 8; ++rr) acc[rr] = fmaf(xs[rr][k], wk, acc[rr]);
  }
  unsigned short sh[8], sl[8];
#pragma unroll
  for (int rr = 0; rr < 8; ++rr) {
    u[(size_t)(r0+rr)*HDIM + hcol] = acc[rr];
    unsigned short hh = f2bf(acc[rr]);
    sh[rr] = hh; sl[rr] = f2bf(acc[rr] - bf2f(hh));
  }
  const int b = r0 >> 11, lw = r0 & 2047;
  size_t ob = ((size_t)(b*HDIM + hcol))*LSEQ + lw;
  *(unsigned long long*)&uth[ob]   = pk4(sh[0],sh[1],sh[2],sh[3]);
  *(unsigned long long*)&uth[ob+4] = pk4(sh[4],sh[5],sh[6],sh[7]);
  *(unsigned long long*)&utl[ob]   = pk4(sl[0],sl[1],sl[2],sl[3]);
  *(unsigned long long*)&utl[ob+4] = pk4(sl[4],sl[5],sl[6],sl[7]);
}

// ---------------- coefficients: one thread per (d,h,n); double transcendentals ONCE
__global__ __launch_bounds__(256) void coef_kernel(
    const float* __restrict__ log_dt, const float* __restrict__ lAr,
    const float* __restrict__ Aim, const float* __restrict__ Cre,
    const float* __restrict__ Cim,
    double2* __restrict__ aa, double2* __restrict__ cc, float* __restrict__ coef) {
  const int gid = blockIdx.x*256 + threadIdx.x;   // d*HN + h*64 + n
  const int d = gid >> 14;
  const int hn = gid & (HN-1);
  const int h = hn >> 6;
  double dt = exp((double)log_dt[d*HDIM + h]);
  double Ar = -exp((double)lAr[gid]);
  double Ai = (double)Aim[gid];
  double dr = Ar*dt, di = Ai*dt;
  double ea = exp(dr);
  double are = ea*cos(di), aim_ = ea*sin(di);
  double inv = 1.0/(Ar*Ar + Ai*Ai);
  double nre = are - 1.0, nim = aim_;
  double qre = (nre*Ar + nim*Ai)*inv;
  double qim = (nim*Ar - nre*Ai)*inv;
  double cre0 = (double)Cre[gid], cim0 = (double)Cim[gid];
  double crd = 2.0*(cre0*qre - cim0*qim);
  double cid = 2.0*(cre0*qim + cim0*qre);
  aa[gid] = make_double2(are, aim_);
  cc[gid] = make_double2(crd, cid);
  double a2r = are*are - aim_*aim_,  a2i = 2.0*are*aim_;
  double a4r = a2r*a2r - a2i*a2i,    a4i = 2.0*a2r*a2i;
  double a8r = a4r*a4r - a4i*a4i,    a8i = 2.0*a4r*a4i;
  double a16r= a8r*a8r - a8i*a8i,    a16i= 2.0*a8r*a8i;
  double a32r= a16r*a16r - a16i*a16i,a32i= 2.0*a16r*a16i;
  double a64r= a32r*a32r - a32i*a32i,a64i= 2.0*a32r*a32i;
  float* cf = coef + (size_t)d*4*HN;
  cf[0*HN + hn] = (float)a64r; cf[1*HN + hn] = (float)a64i;
  cf[2*HN + hn] = (float)crd;  cf[3*HN + hn] = (float)cid;
}

// ---------------- build per-layer matrices; task-parallel: z=0 E2, z=1 Epow, z=2 kv+T
__device__ __forceinline__ void copy_mats4(const unsigned short (*BB)[64][68],
    unsigned short* dst, int h, int tid) {
#pragma unroll
  for (int v = 0; v < 4; ++v) {
    unsigned int* dv = (unsigned int*)(dst + (size_t)v*M1 + (size_t)h*4096);
    for (int uu = tid; uu < 2048; uu += 256) {
      int toff = uu*2;
      int tile = toff >> 9, win = toff & 511;
      int row = (tile>>1)*16 + (win>>5);
      int k   = (tile&1)*32 + (win&31);
      dv[uu] = *(const unsigned int*)&BB[v][row][k];
    }
  }
}

__global__ __launch_bounds__(256) void build_mats(
    const double2* __restrict__ aa, const double2* __restrict__ cc,
    const float* __restrict__ Dv, unsigned short* __restrict__ mats_base) {
  __shared__ unsigned short BB[4][64][68];
  __shared__ float kvs[64];
  const int h = blockIdx.x, d = blockIdx.y, task = blockIdx.z;
  const int tid = threadIdx.x, w = tid >> 6, l = tid & 63;
  const int gid = d*HN + h*64 + l;
  unsigned short* mats = mats_base + (size_t)d*10*M1;
  double2 av = aa[gid];
  double are = av.x, aim_ = av.y;
  double a2r = are*are - aim_*aim_,  a2i = 2.0*are*aim_;
  double a4r = a2r*a2r - a2i*a2i,    a4i = 2.0*a2r*a2i;
  double a8r = a4r*a4r - a4i*a4i,    a8i = 2.0*a4r*a4i;
  double a16r= a8r*a8r - a8i*a8i,    a16i= 2.0*a8r*a8i;
  double a32r= a16r*a16r - a16i*a16i,a32i= 2.0*a16r*a16i;
  double a48r= a32r*a16r - a32i*a16i,a48i= a32r*a16i + a32i*a16r;

  if (task == 0) {
    double pr, pi;
    if      (w == 3) { pr = 1.0;  pi = 0.0;  }
    else if (w == 2) { pr = a16r; pi = a16i; }
    else if (w == 1) { pr = a32r; pi = a32i; }
    else             { pr = a48r; pi = a48i; }
    for (int j = 16*w+15; j >= 16*w; --j) {
      float pf = (float)pr, qf = (float)pi;
      unsigned short hh = f2bf(pf);
      BB[0][l][j] = hh; BB[1][l][j] = f2bf(pf - bf2f(hh));
      hh = f2bf(qf);
      BB[2][l][j] = hh; BB[3][l][j] = f2bf(qf - bf2f(hh));
      double nr = pr*are - pi*aim_, ni = pr*aim_ + pi*are;
      pr = nr; pi = ni;
    }
    __syncthreads();
    copy_mats4(BB, mats, h, tid);
  } else if (task == 1) {
    double pr, pi;
    if      (w == 0) { pr = are; pi = aim_; }
    else if (w == 1) { pr = a16r*are - a16i*aim_; pi = a16r*aim_ + a16i*are; }
    else if (w == 2) { pr = a32r*are - a32i*aim_; pi = a32r*aim_ + a32i*are; }
    else             { pr = a48r*are - a48i*aim_; pi = a48r*aim_ + a48i*are; }
    for (int t = 16*w; t < 16*w+16; ++t) {
      float pf = (float)pr, qf = (float)(-pi);
      unsigned short hh = f2bf(pf);
      BB[0][t][l] = hh; BB[1][t][l] = f2bf(pf - bf2f(hh));
      hh = f2bf(qf);
      BB[2][t][l] = hh; BB[3][t][l] = f2bf(qf - bf2f(hh));
      double nr = pr*are - pi*aim_, ni = pr*aim_ + pi*are;
      pr = nr; pi = ni;
    }
    __syncthreads();
    copy_mats4(BB, mats + (size_t)4*M1, h, tid);
  } else {
    double2 cv = cc[gid];
    double crd = cv.x, cid = cv.y;
    double br, bi2;
    if      (w == 0) { br = 1.0;  bi2 = 0.0;  }
    else if (w == 1) { br = a16r; bi2 = a16i; }
    else if (w == 2) { br = a32r; bi2 = a32i; }
    else             { br = a48r; bi2 = a48i; }
    double tr = crd*br - cid*bi2, ti = crd*bi2 + cid*br;
#pragma unroll
    for (int mm = 0; mm < 16; ++mm) {
      float s = wave_sum64((float)tr);
      if (l == 63) kvs[16*w + mm] = s;
      double nr = tr*are - ti*aim_, ni = tr*aim_ + ti*are;
      tr = nr; ti = ni;
    }
    __syncthreads();
    const float Dh = Dv[d*HDIM + h];
    for (int idx = tid; idx < 4096; idx += 256) {
      int tile = idx >> 9, win = idx & 511;
      int row = (tile>>1)*16 + (win>>5);
      int jj  = (tile&1)*32 + (win&31);
      int dm = row - jj;
      float v = 0.f;
      if (dm >= 0) v = kvs[dm] + (dm == 0 ? Dh : 0.f);
      unsigned short hh = f2bf(v);
      mats[(size_t)8*M1 + (size_t)h*4096 + idx] = hh;
      mats[(size_t)9*M1 + (size_t)h*4096 + idx] = f2bf(v - bf2f(hh));
    }
  }
}

// ---------------- MFMA scan: block = (h, batch), 32 cols = 32 chunks. LDS ~27KB -> high occupancy.
__device__ __forceinline__ void gemm_conv(facc4 (&acc)[2],
    const unsigned short (*UU)[32][72], const bfrag8 (&fT)[2][2], int l) {
#pragma unroll
  for (int kb = 0; kb < 2; ++kb) {
    int koff = kb*32 + (l>>4)*8;
#pragma unroll
    for (int mt = 0; mt < 2; ++mt) {
      int arow = 16*mt + (l&15);
      bfrag8 ah = *(const bfrag8*)&UU[0][arow][koff];
      bfrag8 al = *(const bfrag8*)&UU[1][arow][koff];
      acc[mt] = __builtin_amdgcn_mfma_f32_16x16x32_bf16(ah, fT[0][kb], acc[mt], 0,0,0);
      acc[mt] = __builtin_amdgcn_mfma_f32_16x16x32_bf16(al, fT[0][kb], acc[mt], 0,0,0);
      acc[mt] = __builtin_amdgcn_mfma_f32_16x16x32_bf16(ah, fT[1][kb], acc[mt], 0,0,0);
    }
  }
}

__global__ __launch_bounds__(256) void scan_gemm(
    const unsigned short* __restrict__ uth, const unsigned short* __restrict__ utl,
    const unsigned short* __restrict__ mats, const float* __restrict__ coef,
    unsigned short* __restrict__ zth, unsigned short* __restrict__ ztl) {
  __shared__ unsigned int SM[2][32][68];                  // f32 s_end -> packed w -> z staging
  __shared__ __align__(16) unsigned short UU[2][32][72];  // u splits [chunk][j]
  const int h = blockIdx.x, b = blockIdx.y;
  const int tid = threadIdx.x, w = tid >> 6, l = tid & 63;

  const unsigned short* mh = mats + (size_t)h*4096;
  const int bo0 = (w*2)*512 + (l&15)*32 + (l>>4)*8;
  bfrag8 fE[4][2], fT[2][2];
#pragma unroll
  for (int v = 0; v < 4; ++v) {
    fE[v][0] = *(const bfrag8*)&mh[(size_t)v*M1 + bo0];
    fE[v][1] = *(const bfrag8*)&mh[(size_t)v*M1 + bo0 + 512];
  }
#pragma unroll
  for (int v = 0; v < 2; ++v) {
    fT[v][0] = *(const bfrag8*)&mh[(size_t)(8+v)*M1 + bo0];
    fT[v][1] = *(const bfrag8*)&mh[(size_t)(8+v)*M1 + bo0 + 512];
  }

#pragma unroll
  for (int p = 0; p < 2; ++p) {
    int ch = tid + p*256;
    int sp = ch >> 8;
    int loff = (ch & 255) * 8;
    const unsigned short* src = sp ? utl : uth;
    uint4 v = *(const uint4*)&src[((size_t)(b*HDIM + h))*LSEQ + loff];
    *(uint4*)&UU[sp][loff>>6][loff & 63] = v;
  }
  __syncthreads();

  // ---- GEMM-A: s_end[chunk][n]
  {
    facc4 are[2], aim[2];
#pragma unroll
    for (int mt = 0; mt < 2; ++mt) { are[mt] = (facc4){0.f,0.f,0.f,0.f}; aim[mt] = (facc4){0.f,0.f,0.f,0.f}; }
#pragma unroll
    for (int kb = 0; kb < 2; ++kb) {
      int koff = kb*32 + (l>>4)*8;
#pragma unroll
      for (int mt = 0; mt < 2; ++mt) {
        int arow = 16*mt + (l&15);
        bfrag8 ah = *(const bfrag8*)&UU[0][arow][koff];
        bfrag8 al = *(const bfrag8*)&UU[1][arow][koff];
        are[mt] = __builtin_amdgcn_mfma_f32_16x16x32_bf16(ah, fE[0][kb], are[mt], 0,0,0);
        are[mt] = __builtin_amdgcn_mfma_f32_16x16x32_bf16(al, fE[0][kb], are[mt], 0,0,0);
        are[mt] = __builtin_amdgcn_mfma_f32_16x16x32_bf16(ah, fE[1][kb], are[mt], 0,0,0);
        aim[mt] = __builtin_amdgcn_mfma_f32_16x16x32_bf16(ah, fE[2][kb], aim[mt], 0,0,0);
        aim[mt] = __builtin_amdgcn_mfma_f32_16x16x32_bf16(al, fE[2][kb], aim[mt], 0,0,0);
        aim[mt] = __builtin_amdgcn_mfma_f32_16x16x32_bf16(ah, fE[3][kb], aim[mt], 0,0,0);
      }
    }
#pragma unroll
    for (int mt = 0; mt < 2; ++mt)
#pragma unroll
      for (int r = 0; r < 4; ++r) {
        int colg = 16*mt + 4*(l>>4) + r;
        int ng   = 16*w + (l&15);
        ((float*)&SM[0][0][0])[colg*68 + ng] = are[mt][r];
        ((float*)&SM[1][0][0])[colg*68 + ng] = aim[mt][r];
      }
  }

  bfrag8 fP[4][2];
#pragma unroll
  for (int v = 0; v < 4; ++v) {
    fP[v][0] = *(const bfrag8*)&mh[(size_t)(4+v)*M1 + bo0];
    fP[v][1] = *(const bfrag8*)&mh[(size_t)(4+v)*M1 + bo0 + 512];
  }
  __syncthreads();

  facc4 acc[2];
#pragma unroll
  for (int mt = 0; mt < 2; ++mt) acc[mt] = (facc4){0.f,0.f,0.f,0.f};

  if (w == 0) {
    const int i0 = h*64 + l;
    float a64r = coef[0*HN+i0], a64i = coef[1*HN+i0];
    float cr = coef[2*HN+i0],   ci = coef[3*HN+i0];
    float rr = 0.f, ri = 0.f;
    float* pre = (float*)&SM[0][0][0];
    float* pim = (float*)&SM[1][0][0];
    for (int c = 0; c < 32; ++c) {
      int off = c*68 + l;
      float tre = pre[off], tim = pim[off];
      float wre = fmaf(cr, rr, -(ci*ri));
      float wim = fmaf(cr, ri,  (ci*rr));
      unsigned short hh = f2bf(wre);
      unsigned short lo = f2bf(wre - bf2f(hh));
      ((unsigned int*)pre)[off] = (unsigned)hh | ((unsigned)lo << 16);
      hh = f2bf(wim); lo = f2bf(wim - bf2f(hh));
      ((unsigned int*)pim)[off] = (unsigned)hh | ((unsigned)lo << 16);
      float nr = fmaf(a64r, rr, fmaf(-a64i, ri, tre));
      float ni = fmaf(a64r, ri, fmaf( a64i, rr, tim));
      rr = nr; ri = ni;
    }
  } else {
    gemm_conv(acc, UU, fT, l);   // waves 1-3 overlap the combine
  }
  __syncthreads();
  if (w == 0) gemm_conv(acc, UU, fT, l);

  // ---- GEMM-B: correction, A = packed w from LDS, B = Epow (registers)
  {
#pragma unroll
    for (int kb = 0; kb < 2; ++kb) {
#pragma unroll
      for (int mt = 0; mt < 2; ++mt) {
        int arow = 16*mt + (l&15);
        int ko = kb*32 + (l>>4)*8;
        const unsigned int* p0 = &SM[0][0][0] + arow*68 + ko;
        const unsigned int* p1 = &SM[1][0][0] + arow*68 + ko;
        uint4 q0 = *(const uint4*)p0;
        uint4 q1 = *(const uint4*)(p0 + 4);
        uint4 s0 = *(const uint4*)p1;
        uint4 s1 = *(const uint4*)(p1 + 4);
        bfrag8 wrh = mk8((q0.x&0xffffu)|(q0.y<<16), (q0.z&0xffffu)|(q0.w<<16),
                         (q1.x&0xffffu)|(q1.y<<16), (q1.z&0xffffu)|(q1.w<<16));
        bfrag8 wrl = mk8((q0.x>>16)|(q0.y&0xffff0000u), (q0.z>>16)|(q0.w&0xffff0000u),
                         (q1.x>>16)|(q1.y&0xffff0000u), (q1.z>>16)|(q1.w&0xffff0000u));
        bfrag8 wih = mk8((s0.x&0xffffu)|(s0.y<<16), (s0.z&0xffffu)|(s0.w<<16),
                         (s1.x&0xffffu)|(s1.y<<16), (s1.z&0xffffu)|(s1.w<<16));
        bfrag8 wil = mk8((s0.x>>16)|(s0.y&0xffff0000u), (s0.z>>16)|(s0.w&0xffff0000u),
                         (s1.x>>16)|(s1.y&0xffff0000u), (s1.z>>16)|(s1.w&0xffff0000u));
        acc[mt] = __builtin_amdgcn_mfma_f32_16x16x32_bf16(wrh, fP[0][kb], acc[mt], 0,0,0);
        acc[mt] = __builtin_amdgcn_mfma_f32_16x16x32_bf16(wrl, fP[0][kb], acc[mt], 0,0,0);
        acc[mt] = __builtin_amdgcn_mfma_f32_16x16x32_bf16(wrh, fP[1][kb], acc[mt], 0,0,0);
        acc[mt] = __builtin_amdgcn_mfma_f32_16x16x32_bf16(wih, fP[2][kb], acc[mt], 0,0,0);
        acc[mt] = __builtin_amdgcn_mfma_f32_16x16x32_bf16(wil, fP[2][kb], acc[mt], 0,0,0);
        acc[mt] = __builtin_amdgcn_mfma_f32_16x16x32_bf16(wih, fP[3][kb], acc[mt], 0,0,0);
      }
    }
  }
  __syncthreads();   // SM reads done; reuse SM as z staging

  unsigned short* zb = (unsigned short*)&SM[0][0][0];  // [split][2048] = 8 KB
  const int tg = 16*w + (l&15);
#pragma unroll
  for (int mt = 0; mt < 2; ++mt)
#pragma unroll
    for (int r = 0; r < 4; ++r) {
      int colg = 16*mt + 4*(l>>4) + r;
      float gv = gelu_tanh(acc[mt][r]);
      int lg = colg*64 + tg;
      unsigned short hh = f2bf(gv);
      zb[lg] = hh;
      zb[2048 + lg] = f2bf(gv - bf2f(hh));
    }
  __syncthreads();
#pragma unroll
  for (int p = 0; p < 2; ++p) {
    int idx = tid + p*256;
    int sp = idx >> 8;
    int off8 = (idx & 255) * 8;
    unsigned short* dst = (sp ? ztl : zth) + ((size_t)(b*HDIM + h))*LSEQ + off8;
    *(uint4*)dst = *(const uint4*)&zb[sp*2048 + off8];
  }
}

// ---------------- GLU: A double-buffered LDS; B fragment-tiled direct from global (L2)
__global__ __launch_bounds__(256) void glu_tile(
    const unsigned short* __restrict__ zth, const unsigned short* __restrict__ ztl,
    const unsigned short* __restrict__ wgh, const unsigned short* __restrict__ wgl,
    const float* __restrict__ bias, float* __restrict__ u,
    unsigned short* __restrict__ uth, unsigned short* __restrict__ utl) {
  __shared__ __align__(16) unsigned short LB[2*2*32*LPAD];  // 2 bufs x (ZAh,ZAl); epilogue TT
  const int bx = blockIdx.x, by = blockIdx.y;
  const int tid = threadIdx.x, w = tid >> 6, l = tid & 63;
  const int r0 = bx*64, c0 = by*64;
  const int b = r0 >> 11, l0g = r0 & 2047;
  facc4 acc[4][2];
#pragma unroll
  for (int nf=0;nf<4;++nf)
#pragma unroll
    for (int ag=0;ag<2;++ag) acc[nf][ag] = (facc4){0.f,0.f,0.f,0.f};

  const int aHH = tid >> 3, aL8 = (tid & 7) * 8;   // thread stages both splits at (aHH,aL8)
  uint4 rA0, rA1, nA0, nA1;
  rA0 = *(const uint4*)&zth[((size_t)(b*HDIM + aHH))*LSEQ + l0g + aL8];
  rA1 = *(const uint4*)&ztl[((size_t)(b*HDIM + aHH))*LSEQ + l0g + aL8];
  {
    unsigned short* Zh = LB;
    unsigned short* Zl = LB + 32*LPAD;
    *(uint4*)&Zh[aHH*LPAD + aL8] = rA0;
    *(uint4*)&Zl[aHH*LPAD + aL8] = rA1;
  }
  __syncthreads();

  const int fbase = (l&15)*32 + (l>>4)*8;
  for (int kk = 0; kk < 8; ++kk) {
    if (kk < 7) {
      int kn = (kk+1)*32;
      nA0 = *(const uint4*)&zth[((size_t)(b*HDIM + kn + aHH))*LSEQ + l0g + aL8];
      nA1 = *(const uint4*)&ztl[((size_t)(b*HDIM + kn + aHH))*LSEQ + l0g + aL8];
    }
    const unsigned short* Zh = LB + (kk&1)*(2*32*LPAD);
    const unsigned short* Zl = Zh + 32*LPAD;
    const int hbase = 8*(l>>4);
    const int lrow = 16*w + (l&15);
    union { unsigned short s[8]; bfrag8 f; } Uh, Ul;
#pragma unroll
    for (int j = 0; j < 8; ++j) {
      Uh.s[j] = Zh[(hbase+j)*LPAD + lrow];
      Ul.s[j] = Zl[(hbase+j)*LPAD + lrow];
    }
    bfrag8 afh = Uh.f, afl = Ul.f;
#pragma unroll
    for (int ag=0; ag<2; ++ag)
#pragma unroll
      for (int nf=0; nf<4; ++nf) {
        int grow16 = (c0>>4) + nf + ag*16;         // grow>>4
        size_t fo = ((size_t)grow16*8 + kk)*512 + fbase;
        bfrag8 bh = *(const bfrag8*)&wgh[fo];
        bfrag8 bl = *(const bfrag8*)&wgl[fo];
        acc[nf][ag] = __builtin_amdgcn_mfma_f32_16x16x32_bf16(afh, bh, acc[nf][ag], 0,0,0);
        acc[nf][ag] = __builtin_amdgcn_mfma_f32_16x16x32_bf16(afl, bh, acc[nf][ag], 0,0,0);
        acc[nf][ag] = __builtin_amdgcn_mfma_f32_16x16x32_bf16(afh, bl, acc[nf][ag], 0,0,0);
      }
    if (kk < 7) {
      unsigned short* Zwh = LB + ((kk+1)&1)*(2*32*LPAD);
      unsigned short* Zwl = Zwh + 32*LPAD;
      *(uint4*)&Zwh[aHH*LPAD + aL8] = nA0;
      *(uint4*)&Zwl[aHH*LPAD + aL8] = nA1;
    }
    __syncthreads();
  }

  float* TT = (float*)LB;   // [64 c][68]
#pragma unroll
  for (int nf=0;nf<4;++nf)
#pragma unroll
    for (int r=0;r<4;++r) {
      int m = w*16 + 4*(l>>4) + r;
      int cc2 = 16*nf + (l&15);
      int c = c0 + cc2;
      float av = acc[nf][0][r] + bias[c];
      float gv = acc[nf][1][r] + bias[256+c];
      float val = u[(size_t)(r0+m)*HDIM + c] + av * (1.f/(1.f + expf(-gv)));
      u[(size_t)(r0+m)*HDIM + c] = val;
      TT[cc2*68 + m] = val;
    }
  __syncthreads();
  {
    int cc2 = tid >> 2, mq = (tid & 3)*16;
    size_t ob = ((size_t)(b*HDIM + c0+cc2))*LSEQ + l0g + mq;
#pragma unroll
    for (int q4 = 0; q4 < 16; q4 += 4) {
      float4 v = *(const float4*)&TT[cc2*68 + mq + q4];
      float vv[4] = {v.x,v.y,v.z,v.w};
      unsigned short sh[4], sl[4];
#pragma unroll
      for (int q=0;q<4;++q){ sh[q]=f2bf(vv[q]); sl[q]=f2bf(vv[q]-bf2f(sh[q])); }
      *(unsigned long long*)&uth[ob+q4] = pk4(sh[0],sh[1],sh[2],sh[3]);
      *(unsigned long long*)&utl[ob+q4] = pk4(sl[0],sl[1],sl[2],sl[3]);
    }
  }
}

// ---------------- LayerNorm -> split-bf16 un
__global__ __launch_bounds__(256) void ln_kernel(
    const float* __restrict__ u, const float* __restrict__ g,
    const float* __restrict__ b, unsigned short* __restrict__ unh,
    unsigned short* __restrict__ unl) {
  const int r0 = blockIdx.x * 8;
  const int w = threadIdx.x >> 6;
  const int lane = threadIdx.x & 63;
#pragma unroll
  for (int rr = 0; rr < 2; ++rr) {
    int r = r0 + w*2 + rr;
    float4 v = *(const float4*)&u[(size_t)r*HDIM + lane*4];
    float s = v.x+v.y+v.z+v.w;
    float sq = v.x*v.x + v.y*v.y + v.z*v.z + v.w*v.w;
    s = wave_sum64(s);
    sq = wave_sum64(sq);
    float mu = rdlane(s, 63) * (1.f/256.f);
    float ms = rdlane(sq, 63) * (1.f/256.f);
    float rstd = rsqrtf(ms - mu*mu + 1e-5f);
    float4 gg = *(const float4*)&g[lane*4];
    float4 bb = *(const float4*)&b[lane*4];
    float o[4];
    o[0] = (v.x-mu)*rstd*gg.x + bb.x;
    o[1] = (v.y-mu)*rstd*gg.y + bb.y;
    o[2] = (v.z-mu)*rstd*gg.z + bb.z;
    o[3] = (v.w-mu)*rstd*gg.w + bb.w;
    unsigned short sh[4], sl[4];
#pragma unroll
    for (int q = 0; q < 4; ++q) {
      sh[q] = f2bf(o[q]); sl[q] = f2bf(o[q] - bf2f(sh[q]));
    }
    size_t ob = (size_t)r*HDIM + lane*4;
    *(unsigned long long*)&unh[ob] = pk4(sh[0],sh[1],sh[2],sh[3]);
    *(unsigned long long*)&unl[ob] = pk4(sl[0],sl[1],sl[2],sl[3]);
  }
}

// ---------------- head: 64r x 64c tile, software-pipelined staging
__global__ __launch_bounds__(256) void head_tile(
    const unsigned short* __restrict__ unh, const unsigned short* __restrict__ unl,
    const unsigned short* __restrict__ whh, const unsigned short* __restrict__ whl,
    const float* __restrict__ hb, float* __restrict__ out) {
  __shared__ __align__(16) unsigned short LB[(2*64 + 2*64)*GPAD];
  unsigned short* Ah = LB;
  unsigned short* Al = LB + 64*GPAD;
  unsigned short* Bh = LB + 2*64*GPAD;
  unsigned short* Bl = LB + 3*64*GPAD;
  const int bx = blockIdx.x, by = blockIdx.y;
  const int tid = threadIdx.x, w = tid >> 6, l = tid & 63;
  const int r0 = bx*64, c0 = by*64;
  facc4 acc[4];
#pragma unroll
  for (int nf=0;nf<4;++nf) acc[nf] = (facc4){0.f,0.f,0.f,0.f};

  const int sM = tid >> 2, sC8 = (tid & 3) * 8;
  uint4 rAh, rAl, rBh, rBl;
  rAh = *(const uint4*)&unh[(size_t)(r0+sM)*HDIM + sC8];
  rAl = *(const uint4*)&unl[(size_t)(r0+sM)*HDIM + sC8];
  rBh = *(const uint4*)&whh[(size_t)(c0+sM)*HDIM + sC8];
  rBl = *(const uint4*)&whl[(size_t)(c0+sM)*HDIM + sC8];

  for (int k0 = 0; k0 < HDIM; k0 += 32) {
    if (k0) __syncthreads();
    *(uint4*)&Ah[sM*GPAD + sC8] = rAh;
    *(uint4*)&Al[sM*GPAD + sC8] = rAl;
    *(uint4*)&Bh[sM*GPAD + sC8] = rBh;
    *(uint4*)&Bl[sM*GPAD + sC8] = rBl;
    __syncthreads();
    if (k0 + 32 < HDIM) {
      int kn = k0 + 32;
      rAh = *(const uint4*)&unh[(size_t)(r0+sM)*HDIM + kn + sC8];
      rAl = *(const uint4*)&unl[(size_t)(r0+sM)*HDIM + kn + sC8];
      rBh = *(const uint4*)&whh[(size_t)(c0+sM)*HDIM + kn + sC8];
      rBl = *(const uint4*)&whl[(size_t)(c0+sM)*HDIM + kn + sC8];
    }
    const int koff = (l>>4)*8;
    const int arow = w*16 + (l&15);
    bfrag8 afh = *(const bfrag8*)&Ah[arow*GPAD + koff];
    bfrag8 afl = *(const bfrag8*)&Al[arow*GPAD + koff];
#pragma unroll
    for (int nf=0; nf<4; ++nf) {
      int brow = 16*nf + (l&15);
      bfrag8 bh = *(const bfrag8*)&Bh[brow*GPAD + koff];
      bfrag8 bl = *(const bfrag8*)&Bl[brow*GPAD + koff];
      acc[nf] = __builtin_amdgcn_mfma_f32_16x16x32_bf16(afh, bh, acc[nf], 0,0,0);
      acc[nf] = __builtin_amdgcn_mfma_f32_16x16x32_bf16(afl, bh, acc[nf], 0,0,0);
      acc[nf] = __builtin_amdgcn_mfma_f32_16x16x32_bf16(afh, bl, acc[nf], 0,0,0);
    }
  }
#pragma unroll
  for (int nf=0;nf<4;++nf) {
    int c = c0 + 16*nf + (l&15);
    if (c < OUTC) {
#pragma unroll
      for (int r=0;r<4;++r) {
        int m = w*16 + 4*(l>>4) + r;
        out[(size_t)(r0+m)*OUTC + c] = acc[nf][r] + hb[c];
      }
    }
  }
}

// ---------------- weight prep: GLU weights -> fragment-tiled split layout
__global__ void prep_wglu(const float* __restrict__ w,
    unsigned short* __restrict__ oh, unsigned short* __restrict__ ol) {
  __shared__ float t[32][33];
  int d = blockIdx.z, k0 = blockIdx.y*32, n0 = blockIdx.x*32;
  int tx = threadIdx.x, ty = threadIdx.y;
#pragma unroll
  for (int i = 0; i < 32; i += 8)
    t[ty+i][tx] = w[((size_t)(d*HDIM + k0+ty+i))*512 + n0+tx];   // t[kk][nn]
  __syncthreads();
  size_t dbase = (size_t)d*512*HDIM;
#pragma unroll
  for (int i = 0; i < 32; i += 8) {
    int r = n0 + ty + i;     // output-col row
    int k = k0 + tx;
    float v = t[tx][ty+i];
    size_t o = dbase + ((size_t)(r>>4)*8 + (k>>5))*512 + (r&15)*32 + (k&31);
    unsigned short hh = f2bf(v);
    oh[o] = hh; ol[o] = f2bf(v - bf2f(hh));
  }
}

__global__ void prep_whead(const float* __restrict__ w,
    unsigned short* __restrict__ oh, unsigned short* __restrict__ ol) {
  __shared__ float t[32][33];
  int k0 = blockIdx.y*32, n0 = blockIdx.x*32;
  int tx = threadIdx.x, ty = threadIdx.y;
#pragma unroll
  for (int i = 0; i < 32; i += 8)
    t[ty+i][tx] = (n0+tx < OUTC) ? w[(size_t)(k0+ty+i)*OUTC + n0+tx] : 0.f;
  __syncthreads();
#pragma unroll
  for (int i = 0; i < 32; i += 8) {
    float v = t[tx][ty+i];
    size_t o = (size_t)(n0+ty+i)*HDIM + k0+tx;
    unsigned short hh = f2bf(v);
    oh[o] = hh; ol[o] = f2bf(v - bf2f(hh));
  }
}

extern "C" void kernel_launch(void* const* d_in, const int* in_sizes, int n_in,
                              void* d_out, int out_size, void* d_ws, size_t ws_size,
                              hipStream_t stream) {
  const float* x       = (const float*)d_in[0];
  const float* proj_w  = (const float*)d_in[1];
  const float* proj_b  = (const float*)d_in[2];
  const float* log_dt  = (const float*)d_in[3];
  const float* lAr     = (const float*)d_in[4];
  const float* Aim     = (const float*)d_in[5];
  const float* Cre     = (const float*)d_in[6];
  const float* Cim     = (const float*)d_in[7];
  const float* Dp      = (const float*)d_in[8];
  const float* out_w   = (const float*)d_in[9];
  const float* out_b   = (const float*)d_in[10];
  const float* ln_g    = (const float*)d_in[11];
  const float* ln_b    = (const float*)d_in[12];
  const float* head_w  = (const float*)d_in[13];
  const float* head_b  = (const float*)d_in[14];
  float* outp = (float*)d_out;

  size_t fixed = (size_t)NROWS*HDIM*4          // u fp32
               + (size_t)NROWS*HDIM*2*4        // uth, utl, zth, ztl
               + (size_t)4*512*HDIM*2*2        // wgh, wgl
               + (size_t)HDIM*HDIM*2*2         // whh, whl
               + (size_t)NDEPTH*4*HN*4         // coef
               + (size_t)2*NDEPTH*HN*16;       // aa, cc double2
  size_t need_small = fixed + (size_t)10*M1*2;
  size_t need_big   = fixed + (size_t)NDEPTH*10*M1*2;
  if (ws_size < need_small) return;
  const bool big = (ws_size >= need_big);

  char* p = (char*)d_ws;
  float* u    = (float*)p;            p += (size_t)NROWS*HDIM*4;
  unsigned short* uth = (unsigned short*)p; p += (size_t)NROWS*HDIM*2;
  unsigned short* utl = (unsigned short*)p; p += (size_t)NROWS*HDIM*2;
  unsigned short* zth = (unsigned short*)p; p += (size_t)NROWS*HDIM*2;
  unsigned short* ztl = (unsigned short*)p; p += (size_t)NROWS*HDIM*2;
  unsigned short* wgh = (unsigned short*)p; p += (size_t)4*512*HDIM*2;
  unsigned short* wgl = (unsigned short*)p; p += (size_t)4*512*HDIM*2;
  unsigned short* whh = (unsigned short*)p; p += (size_t)HDIM*HDIM*2;
  unsigned short* whl = (unsigned short*)p; p += (size_t)HDIM*HDIM*2;
  float* coef = (float*)p;            p += (size_t)NDEPTH*4*HN*4;
  double2* aa = (double2*)p;          p += (size_t)NDEPTH*HN*16;
  double2* cc = (double2*)p;          p += (size_t)NDEPTH*HN*16;
  unsigned short* mats = (unsigned short*)p;   // flex region (1 or 4 layers)
  unsigned short* unh = uth;  // reuse after last layer
  unsigned short* unl = utl;

  coef_kernel<<<NDEPTH*HN/256, 256, 0, stream>>>(log_dt, lAr, Aim, Cre, Cim, aa, cc, coef);
  prep_wglu<<<dim3(16, 8, 4), dim3(32,8), 0, stream>>>(out_w, wgh, wgl);
  prep_whead<<<dim3(8, 8), dim3(32,8), 0, stream>>>(head_w, whh, whl);
  if (big) {
    build_mats<<<dim3(HDIM, NDEPTH, 3), 256, 0, stream>>>(aa, cc, Dp, mats);
  }
  proj_kernel<<<NROWS/8, 256, 0, stream>>>(x, proj_w, proj_b, u, uth, utl);

  for (int d = 0; d < NDEPTH; ++d) {
    if (!big) {
      build_mats<<<dim3(HDIM, 1, 3), 256, 0, stream>>>(
          aa + (size_t)d*HN, cc + (size_t)d*HN, Dp + d*HDIM, mats);
    }
    unsigned short* md = mats + (big ? (size_t)d*10*M1 : 0);
    scan_gemm<<<dim3(HDIM, NBATCH), 256, 0, stream>>>(
        uth, utl, md, coef + (size_t)d*4*HN, zth, ztl);
    glu_tile<<<dim3(NROWS/64, 4), 256, 0, stream>>>(
        zth, ztl, wgh + (size_t)d*512*HDIM, wgl + (size_t)d*512*HDIM,
        out_b + d*512, u, uth, utl);
  }

  ln_kernel<<<NROWS/8, 256, 0, stream>>>(u, ln_g, ln_b, unh, unl);
  head_tile<<<dim3(NROWS/64, 4), 256, 0, stream>>>(unh, unl, whh, whl, head_b, outp);
}

// Round 16
// 268.538 us; speedup vs baseline: 1.3357x; 1.3357x over previous
//
#include <hip/hip_runtime.h>
#include <math.h>

#define HDIM 256
#define NSTATE 64
#define NDEPTH 4
#define LSEQ 2048
#define NBATCH 8
#define NROWS (NBATCH*LSEQ)   // 16384
#define HN (HDIM*NSTATE)      // 16384
#define INDIM 51
#define OUTC 204
#define M1 (256*4096)         // shorts per variant (256 h x 64x64)
#define GPAD 40               // padded k-stride (shorts) for B tiles
#define LPAD 74               // padded l-stride (shorts) for z^T tiles (bank-spread)

typedef short bfrag8 __attribute__((ext_vector_type(8)));
typedef float facc4 __attribute__((ext_vector_type(4)));

// ---------------- helpers ----------------
template<int CTRL>
__device__ __forceinline__ float dpp_add(float x) {
  int y = __builtin_amdgcn_update_dpp(0, __float_as_int(x), CTRL, 0xf, 0xf, true);
  return x + __int_as_float(y);
}
__device__ __forceinline__ float wave_sum64(float x) {
  x = dpp_add<0x111>(x);
  x = dpp_add<0x112>(x);
  x = dpp_add<0x114>(x);
  x = dpp_add<0x118>(x);
  x = dpp_add<0x142>(x);
  x = dpp_add<0x143>(x);
  return x;   // total in lane 63
}
__device__ __forceinline__ float rdlane(float v, int lane) {
  return __int_as_float(__builtin_amdgcn_readlane(__float_as_int(v), lane));
}
__device__ __forceinline__ float gelu_tanh(float x) {
  float x3 = x*x*x;
  return 0.5f*x*(1.f + tanhf(0.7978845608028654f*(x + 0.044715f*x3)));
}
__device__ __forceinline__ unsigned short f2bf(float x) {
  unsigned u = __float_as_uint(x);
  unsigned r = (u + 0x7FFFu + ((u >> 16) & 1u)) >> 16;
  return (unsigned short)r;
}
__device__ __forceinline__ float bf2f(unsigned short h) {
  return __uint_as_float(((unsigned)h) << 16);
}
__device__ __forceinline__ bfrag8 mk8(unsigned a, unsigned b, unsigned c, unsigned d) {
  union { unsigned u[4]; bfrag8 f; } U;
  U.u[0]=a; U.u[1]=b; U.u[2]=c; U.u[3]=d; return U.f;
}
__device__ __forceinline__ unsigned long long pk4(unsigned short a,unsigned short b,
                                                  unsigned short c,unsigned short d){
  return (unsigned long long)a | ((unsigned long long)b<<16) |
         ((unsigned long long)c<<32) | ((unsigned long long)d<<48);
}

// ---------------- input projection: x[16384,51] @ w[51,256] + b -> u fp32 + uth/utl splits
__global__ __launch_bounds__(256) void proj_kernel(
    const float* __restrict__ x, const float* __restrict__ w,
    const float* __restrict__ bias, float* __restrict__ u,
    unsigned short* __restrict__ uth, unsigned short* __restrict__ utl) {
  __shared__ float xs[8][52];
  const int r0 = blockIdx.x * 8;
  const int tid = threadIdx.x;
  for (int idx = tid; idx < 8*INDIM; idx += 256) {
    int rr = idx / INDIM, k = idx % INDIM;
    xs[rr][k] = x[(size_t)(r0+rr)*INDIM + k];
  }
  __syncthreads();
  const int hcol = tid;
  float acc[8];
  const float bb = bias[hcol];
#pragma unroll
  for (int rr = 0; rr < 8; ++rr) acc[rr] = bb;
#pragma unroll
  for (int k = 0; k < 48; k += 4) {
    float w0 = w[(k+0)*HDIM + hcol];
    float w1 = w[(k+1)*HDIM + hcol];
    float w2 = w[(k+2)*HDIM + hcol];
    float w3 = w[(k+3)*HDIM + hcol];
#pragma unroll
    for (int rr = 0; rr < 8; ++rr) {
      float4 xv = *(const float4*)&xs[rr][k];
      acc[rr] = fmaf(xv.x, w0, acc[rr]);
      acc[rr] = fmaf(xv.y, w1, acc[rr]);
      acc[rr] = fmaf(xv.z, w2, acc[rr]);
      acc[rr] = fmaf(xv.w, w3, acc[rr]);
    }
  }
#pragma unroll
  for (int k = 48; k < INDIM; ++k) {
    float wk = w[k*HDIM + hcol];
#pragma unroll
    for (int rr = 0; rr < 8; ++rr) acc[rr] = fmaf(xs[rr][k], wk, acc[rr]);
  }
  unsigned short sh[8], sl[8];
#pragma unroll
  for (int rr = 0; rr < 8; ++rr) {
    u[(size_t)(r0+rr)*HDIM + hcol] = acc[rr];
    unsigned short hh = f2bf(acc[rr]);
    sh[rr] = hh; sl[rr] = f2bf(acc[rr] - bf2f(hh));
  }
  const int b = r0 >> 11, lw = r0 & 2047;
  size_t ob = ((size_t)(b*HDIM + hcol))*LSEQ + lw;
  *(unsigned long long*)&uth[ob]   = pk4(sh[0],sh[1],sh[2],sh[3]);
  *(unsigned long long*)&uth[ob+4] = pk4(sh[4],sh[5],sh[6],sh[7]);
  *(unsigned long long*)&utl[ob]   = pk4(sl[0],sl[1],sl[2],sl[3]);
  *(unsigned long long*)&utl[ob+4] = pk4(sl[4],sl[5],sl[6],sl[7]);
}

// ---------------- coefficients: one thread per (d,h,n); double transcendentals ONCE
__global__ __launch_bounds__(256) void coef_kernel(
    const float* __restrict__ log_dt, const float* __restrict__ lAr,
    const float* __restrict__ Aim, const float* __restrict__ Cre,
    const float* __restrict__ Cim,
    double2* __restrict__ aa, double2* __restrict__ cc, float* __restrict__ coef) {
  const int gid = blockIdx.x*256 + threadIdx.x;   // d*HN + h*64 + n
  const int d = gid >> 14;
  const int hn = gid & (HN-1);
  const int h = hn >> 6;
  double dt = exp((double)log_dt[d*HDIM + h]);
  double Ar = -exp((double)lAr[gid]);
  double Ai = (double)Aim[gid];
  double dr = Ar*dt, di = Ai*dt;
  double ea = exp(dr);
  double are = ea*cos(di), aim_ = ea*sin(di);
  double inv = 1.0/(Ar*Ar + Ai*Ai);
  double nre = are - 1.0, nim = aim_;
  double qre = (nre*Ar + nim*Ai)*inv;
  double qim = (nim*Ar - nre*Ai)*inv;
  double cre0 = (double)Cre[gid], cim0 = (double)Cim[gid];
  double crd = 2.0*(cre0*qre - cim0*qim);
  double cid = 2.0*(cre0*qim + cim0*qre);
  aa[gid] = make_double2(are, aim_);
  cc[gid] = make_double2(crd, cid);
  double a2r = are*are - aim_*aim_,  a2i = 2.0*are*aim_;
  double a4r = a2r*a2r - a2i*a2i,    a4i = 2.0*a2r*a2i;
  double a8r = a4r*a4r - a4i*a4i,    a8i = 2.0*a4r*a4i;
  double a16r= a8r*a8r - a8i*a8i,    a16i= 2.0*a8r*a8i;
  double a32r= a16r*a16r - a16i*a16i,a32i= 2.0*a16r*a16i;
  double a64r= a32r*a32r - a32i*a32i,a64i= 2.0*a32r*a32i;
  float* cf = coef + (size_t)d*4*HN;
  cf[0*HN + hn] = (float)a64r; cf[1*HN + hn] = (float)a64i;
  cf[2*HN + hn] = (float)crd;  cf[3*HN + hn] = (float)cid;
}

// ---------------- build per-layer matrices; task-parallel: z=0 E2, z=1 Epow, z=2 kv+T
__device__ __forceinline__ void copy_mats4(const unsigned short (*BB)[64][68],
    unsigned short* dst, int h, int tid) {
#pragma unroll
  for (int v = 0; v < 4; ++v) {
    unsigned int* dv = (unsigned int*)(dst + (size_t)v*M1 + (size_t)h*4096);
    for (int uu = tid; uu < 2048; uu += 256) {
      int toff = uu*2;
      int tile = toff >> 9, win = toff & 511;
      int row = (tile>>1)*16 + (win>>5);
      int k   = (tile&1)*32 + (win&31);
      dv[uu] = *(const unsigned int*)&BB[v][row][k];
    }
  }
}

__global__ __launch_bounds__(256) void build_mats(
    const double2* __restrict__ aa, const double2* __restrict__ cc,
    const float* __restrict__ Dv, unsigned short* __restrict__ mats_base) {
  __shared__ unsigned short BB[4][64][68];
  __shared__ float kvs[64];
  const int h = blockIdx.x, d = blockIdx.y, task = blockIdx.z;
  const int tid = threadIdx.x, w = tid >> 6, l = tid & 63;
  const int gid = d*HN + h*64 + l;
  unsigned short* mats = mats_base + (size_t)d*10*M1;
  double2 av = aa[gid];
  double are = av.x, aim_ = av.y;
  double a2r = are*are - aim_*aim_,  a2i = 2.0*are*aim_;
  double a4r = a2r*a2r - a2i*a2i,    a4i = 2.0*a2r*a2i;
  double a8r = a4r*a4r - a4i*a4i,    a8i = 2.0*a4r*a4i;
  double a16r= a8r*a8r - a8i*a8i,    a16i= 2.0*a8r*a8i;
  double a32r= a16r*a16r - a16i*a16i,a32i= 2.0*a16r*a16i;
  double a48r= a32r*a16r - a32i*a16i,a48i= a32r*a16i + a32i*a16r;

  if (task == 0) {
    double pr, pi;
    if      (w == 3) { pr = 1.0;  pi = 0.0;  }
    else if (w == 2) { pr = a16r; pi = a16i; }
    else if (w == 1) { pr = a32r; pi = a32i; }
    else             { pr = a48r; pi = a48i; }
    for (int j = 16*w+15; j >= 16*w; --j) {
      float pf = (float)pr, qf = (float)pi;
      unsigned short hh = f2bf(pf);
      BB[0][l][j] = hh; BB[1][l][j] = f2bf(pf - bf2f(hh));
      hh = f2bf(qf);
      BB[2][l][j] = hh; BB[3][l][j] = f2bf(qf - bf2f(hh));
      double nr = pr*are - pi*aim_, ni = pr*aim_ + pi*are;
      pr = nr; pi = ni;
    }
    __syncthreads();
    copy_mats4(BB, mats, h, tid);
  } else if (task == 1) {
    double pr, pi;
    if      (w == 0) { pr = are; pi = aim_; }
    else if (w == 1) { pr = a16r*are - a16i*aim_; pi = a16r*aim_ + a16i*are; }
    else if (w == 2) { pr = a32r*are - a32i*aim_; pi = a32r*aim_ + a32i*are; }
    else             { pr = a48r*are - a48i*aim_; pi = a48r*aim_ + a48i*are; }
    for (int t = 16*w; t < 16*w+16; ++t) {
      float pf = (float)pr, qf = (float)(-pi);
      unsigned short hh = f2bf(pf);
      BB[0][t][l] = hh; BB[1][t][l] = f2bf(pf - bf2f(hh));
      hh = f2bf(qf);
      BB[2][t][l] = hh; BB[3][t][l] = f2bf(qf - bf2f(hh));
      double nr = pr*are - pi*aim_, ni = pr*aim_ + pi*are;
      pr = nr; pi = ni;
    }
    __syncthreads();
    copy_mats4(BB, mats + (size_t)4*M1, h, tid);
  } else {
    double2 cv = cc[gid];
    double crd = cv.x, cid = cv.y;
    double br, bi2;
    if      (w == 0) { br = 1.0;  bi2 = 0.0;  }
    else if (w == 1) { br = a16r; bi2 = a16i; }
    else if (w == 2) { br = a32r; bi2 = a32i; }
    else             { br = a48r; bi2 = a48i; }
    double tr = crd*br - cid*bi2, ti = crd*bi2 + cid*br;
#pragma unroll
    for (int mm = 0; mm < 16; ++mm) {
      float s = wave_sum64((float)tr);
      if (l == 63) kvs[16*w + mm] = s;
      double nr = tr*are - ti*aim_, ni = tr*aim_ + ti*are;
      tr = nr; ti = ni;
    }
    __syncthreads();
    const float Dh = Dv[d*HDIM + h];
    for (int idx = tid; idx < 4096; idx += 256) {
      int tile = idx >> 9, win = idx & 511;
      int row = (tile>>1)*16 + (win>>5);
      int jj  = (tile&1)*32 + (win&31);
      int dm = row - jj;
      float v = 0.f;
      if (dm >= 0) v = kvs[dm] + (dm == 0 ? Dh : 0.f);
      unsigned short hh = f2bf(v);
      mats[(size_t)8*M1 + (size_t)h*4096 + idx] = hh;
      mats[(size_t)9*M1 + (size_t)h*4096 + idx] = f2bf(v - bf2f(hh));
    }
  }
}

// ---------------- MFMA scan: block = (h, batch), 32 cols = 32 chunks. LDS ~27KB -> high occupancy.
__device__ __forceinline__ void gemm_conv(facc4 (&acc)[2],
    const unsigned short (*UU)[32][72], const bfrag8 (&fT)[2][2], int l) {
#pragma unroll
  for (int kb = 0; kb < 2; ++kb) {
    int koff = kb*32 + (l>>4)*8;
#pragma unroll
    for (int mt = 0; mt < 2; ++mt) {
      int arow = 16*mt + (l&15);
      bfrag8 ah = *(const bfrag8*)&UU[0][arow][koff];
      bfrag8 al = *(const bfrag8*)&UU[1][arow][koff];
      acc[mt] = __builtin_amdgcn_mfma_f32_16x16x32_bf16(ah, fT[0][kb], acc[mt], 0,0,0);
      acc[mt] = __builtin_amdgcn_mfma_f32_16x16x32_bf16(al, fT[0][kb], acc[mt], 0,0,0);
      acc[mt] = __builtin_amdgcn_mfma_f32_16x16x32_bf16(ah, fT[1][kb], acc[mt], 0,0,0);
    }
  }
}

__global__ __launch_bounds__(256) void scan_gemm(
    const unsigned short* __restrict__ uth, const unsigned short* __restrict__ utl,
    const unsigned short* __restrict__ mats, const float* __restrict__ coef,
    unsigned short* __restrict__ zth, unsigned short* __restrict__ ztl) {
  __shared__ unsigned int SM[2][32][68];                  // f32 s_end -> packed w -> z staging
  __shared__ __align__(16) unsigned short UU[2][32][72];  // u splits [chunk][j]
  const int h = blockIdx.x, b = blockIdx.y;
  const int tid = threadIdx.x, w = tid >> 6, l = tid & 63;

  const unsigned short* mh = mats + (size_t)h*4096;
  const int bo0 = (w*2)*512 + (l&15)*32 + (l>>4)*8;
  bfrag8 fE[4][2], fT[2][2];
#pragma unroll
  for (int v = 0; v < 4; ++v) {
    fE[v][0] = *(const bfrag8*)&mh[(size_t)v*M1 + bo0];
    fE[v][1] = *(const bfrag8*)&mh[(size_t)v*M1 + bo0 + 512];
  }
#pragma unroll
  for (int v = 0; v < 2; ++v) {
    fT[v][0] = *(const bfrag8*)&mh[(size_t)(8+v)*M1 + bo0];
    fT[v][1] = *(const bfrag8*)&mh[(size_t)(8+v)*M1 + bo0 + 512];
  }

#pragma unroll
  for (int p = 0; p < 2; ++p) {
    int ch = tid + p*256;
    int sp = ch >> 8;
    int loff = (ch & 255) * 8;
    const unsigned short* src = sp ? utl : uth;
    uint4 v = *(const uint4*)&src[((size_t)(b*HDIM + h))*LSEQ + loff];
    *(uint4*)&UU[sp][loff>>6][loff & 63] = v;
  }
  __syncthreads();

  // ---- GEMM-A: s_end[chunk][n]
  {
    facc4 are[2], aim[2];
#pragma unroll
    for (int mt = 0; mt < 2; ++mt) { are[mt] = (facc4){0.f,0.f,0.f,0.f}; aim[mt] = (facc4){0.f,0.f,0.f,0.f}; }
#pragma unroll
    for (int kb = 0; kb < 2; ++kb) {
      int koff = kb*32 + (l>>4)*8;
#pragma unroll
      for (int mt = 0; mt < 2; ++mt) {
        int arow = 16*mt + (l&15);
        bfrag8 ah = *(const bfrag8*)&UU[0][arow][koff];
        bfrag8 al = *(const bfrag8*)&UU[1][arow][koff];
        are[mt] = __builtin_amdgcn_mfma_f32_16x16x32_bf16(ah, fE[0][kb], are[mt], 0,0,0);
        are[mt] = __builtin_amdgcn_mfma_f32_16x16x32_bf16(al, fE[0][kb], are[mt], 0,0,0);
        are[mt] = __builtin_amdgcn_mfma_f32_16x16x32_bf16(ah, fE[1][kb], are[mt], 0,0,0);
        aim[mt] = __builtin_amdgcn_mfma_f32_16x16x32_bf16(ah, fE[2][kb], aim[mt], 0,0,0);
        aim[mt] = __builtin_amdgcn_mfma_f32_16x16x32_bf16(al, fE[2][kb], aim[mt], 0,0,0);
        aim[mt] = __builtin_amdgcn_mfma_f32_16x16x32_bf16(ah, fE[3][kb], aim[mt], 0,0,0);
      }
    }
#pragma unroll
    for (int mt = 0; mt < 2; ++mt)
#pragma unroll
      for (int r = 0; r < 4; ++r) {
        int colg = 16*mt + 4*(l>>4) + r;
        int ng   = 16*w + (l&15);
        ((float*)&SM[0][0][0])[colg*68 + ng] = are[mt][r];
        ((float*)&SM[1][0][0])[colg*68 + ng] = aim[mt][r];
      }
  }

  bfrag8 fP[4][2];
#pragma unroll
  for (int v = 0; v < 4; ++v) {
    fP[v][0] = *(const bfrag8*)&mh[(size_t)(4+v)*M1 + bo0];
    fP[v][1] = *(const bfrag8*)&mh[(size_t)(4+v)*M1 + bo0 + 512];
  }
  __syncthreads();

  facc4 acc[2];
#pragma unroll
  for (int mt = 0; mt < 2; ++mt) acc[mt] = (facc4){0.f,0.f,0.f,0.f};

  if (w == 0) {
    const int i0 = h*64 + l;
    float a64r = coef[0*HN+i0], a64i = coef[1*HN+i0];
    float cr = coef[2*HN+i0],   ci = coef[3*HN+i0];
    float rr = 0.f, ri = 0.f;
    float* pre = (float*)&SM[0][0][0];
    float* pim = (float*)&SM[1][0][0];
    for (int c = 0; c < 32; ++c) {
      int off = c*68 + l;
      float tre = pre[off], tim = pim[off];
      float wre = fmaf(cr, rr, -(ci*ri));
      float wim = fmaf(cr, ri,  (ci*rr));
      unsigned short hh = f2bf(wre);
      unsigned short lo = f2bf(wre - bf2f(hh));
      ((unsigned int*)pre)[off] = (unsigned)hh | ((unsigned)lo << 16);
      hh = f2bf(wim); lo = f2bf(wim - bf2f(hh));
      ((unsigned int*)pim)[off] = (unsigned)hh | ((unsigned)lo << 16);
      float nr = fmaf(a64r, rr, fmaf(-a64i, ri, tre));
      float ni = fmaf(a64r, ri, fmaf( a64i, rr, tim));
      rr = nr; ri = ni;
    }
  } else {
    gemm_conv(acc, UU, fT, l);   // waves 1-3 overlap the combine
  }
  __syncthreads();
  if (w == 0) gemm_conv(acc, UU, fT, l);

  // ---- GEMM-B: correction, A = packed w from LDS, B = Epow (registers)
  {
#pragma unroll
    for (int kb = 0; kb < 2; ++kb) {
#pragma unroll
      for (int mt = 0; mt < 2; ++mt) {
        int arow = 16*mt + (l&15);
        int ko = kb*32 + (l>>4)*8;
        const unsigned int* p0 = &SM[0][0][0] + arow*68 + ko;
        const unsigned int* p1 = &SM[1][0][0] + arow*68 + ko;
        uint4 q0 = *(const uint4*)p0;
        uint4 q1 = *(const uint4*)(p0 + 4);
        uint4 s0 = *(const uint4*)p1;
        uint4 s1 = *(const uint4*)(p1 + 4);
        bfrag8 wrh = mk8((q0.x&0xffffu)|(q0.y<<16), (q0.z&0xffffu)|(q0.w<<16),
                         (q1.x&0xffffu)|(q1.y<<16), (q1.z&0xffffu)|(q1.w<<16));
        bfrag8 wrl = mk8((q0.x>>16)|(q0.y&0xffff0000u), (q0.z>>16)|(q0.w&0xffff0000u),
                         (q1.x>>16)|(q1.y&0xffff0000u), (q1.z>>16)|(q1.w&0xffff0000u));
        bfrag8 wih = mk8((s0.x&0xffffu)|(s0.y<<16), (s0.z&0xffffu)|(s0.w<<16),
                         (s1.x&0xffffu)|(s1.y<<16), (s1.z&0xffffu)|(s1.w<<16));
        bfrag8 wil = mk8((s0.x>>16)|(s0.y&0xffff0000u), (s0.z>>16)|(s0.w&0xffff0000u),
                         (s1.x>>16)|(s1.y&0xffff0000u), (s1.z>>16)|(s1.w&0xffff0000u));
        acc[mt] = __builtin_amdgcn_mfma_f32_16x16x32_bf16(wrh, fP[0][kb], acc[mt], 0,0,0);
        acc[mt] = __builtin_amdgcn_mfma_f32_16x16x32_bf16(wrl, fP[0][kb], acc[mt], 0,0,0);
        acc[mt] = __builtin_amdgcn_mfma_f32_16x16x32_bf16(wrh, fP[1][kb], acc[mt], 0,0,0);
        acc[mt] = __builtin_amdgcn_mfma_f32_16x16x32_bf16(wih, fP[2][kb], acc[mt], 0,0,0);
        acc[mt] = __builtin_amdgcn_mfma_f32_16x16x32_bf16(wil, fP[2][kb], acc[mt], 0,0,0);
        acc[mt] = __builtin_amdgcn_mfma_f32_16x16x32_bf16(wih, fP[3][kb], acc[mt], 0,0,0);
      }
    }
  }
  __syncthreads();   // SM reads done; reuse SM as z staging

  unsigned short* zb = (unsigned short*)&SM[0][0][0];  // [split][2048] = 8 KB
  const int tg = 16*w + (l&15);
#pragma unroll
  for (int mt = 0; mt < 2; ++mt)
#pragma unroll
    for (int r = 0; r < 4; ++r) {
      int colg = 16*mt + 4*(l>>4) + r;
      float gv = gelu_tanh(acc[mt][r]);
      int lg = colg*64 + tg;
      unsigned short hh = f2bf(gv);
      zb[lg] = hh;
      zb[2048 + lg] = f2bf(gv - bf2f(hh));
    }
  __syncthreads();
#pragma unroll
  for (int p = 0; p < 2; ++p) {
    int idx = tid + p*256;
    int sp = idx >> 8;
    int off8 = (idx & 255) * 8;
    unsigned short* dst = (sp ? ztl : zth) + ((size_t)(b*HDIM + h))*LSEQ + off8;
    *(uint4*)dst = *(const uint4*)&zb[sp*2048 + off8];
  }
}

// ---------------- GLU: reads z^T directly; software-pipelined staging (prefetch k+1 regs)
__global__ __launch_bounds__(256) void glu_tile(
    const unsigned short* __restrict__ zth, const unsigned short* __restrict__ ztl,
    const unsigned short* __restrict__ wgh, const unsigned short* __restrict__ wgl,
    const float* __restrict__ bias, float* __restrict__ u,
    unsigned short* __restrict__ uth, unsigned short* __restrict__ utl) {
  __shared__ __align__(16) unsigned short LB[2*32*LPAD + 2*128*GPAD];  // ZAh ZAl Bh Bl; epilogue TT
  unsigned short* ZAh = LB;
  unsigned short* ZAl = LB + 32*LPAD;
  unsigned short* Bh  = LB + 2*32*LPAD;
  unsigned short* Bl  = LB + 2*32*LPAD + 128*GPAD;
  const int bx = blockIdx.x, by = blockIdx.y;
  const int tid = threadIdx.x, w = tid >> 6, l = tid & 63;
  const int r0 = bx*64, c0 = by*64;
  const int b = r0 >> 11, l0g = r0 & 2047;
  facc4 acc[4][2];
#pragma unroll
  for (int nf=0;nf<4;++nf)
#pragma unroll
    for (int ag=0;ag<2;++ag) acc[nf][ag] = (facc4){0.f,0.f,0.f,0.f};

  // per-thread staging coordinates (fixed across k-steps)
  const int aIdx0 = tid & 255;
  const int aHH0 = aIdx0 >> 3,  aL80  = (aIdx0 & 7) * 8;
  const int aIdx1 = (tid + 256) & 255;
  const int aHH1 = aIdx1 >> 3,  aL81  = (aIdx1 & 7) * 8;
  const int bM0 = tid >> 2,        bC80 = (tid & 3) * 8;
  const int bM1 = (tid+256) >> 2,  bC81 = bC80;
  const int bG0 = c0 + (bM0 & 63) + ((bM0 & 64) ? 256 : 0);
  const int bG1 = c0 + (bM1 & 63) + ((bM1 & 64) ? 256 : 0);

  uint4 rA0, rA1, rBh0, rBl0, rBh1, rBl1;
  // prologue: k0 = 0 loads
  rA0 = *(const uint4*)&zth[((size_t)(b*HDIM + aHH0))*LSEQ + l0g + aL80];
  rA1 = *(const uint4*)&ztl[((size_t)(b*HDIM + aHH1))*LSEQ + l0g + aL81];
  rBh0 = *(const uint4*)&wgh[(size_t)bG0*HDIM + bC80];
  rBl0 = *(const uint4*)&wgl[(size_t)bG0*HDIM + bC80];
  rBh1 = *(const uint4*)&wgh[(size_t)bG1*HDIM + bC81];
  rBl1 = *(const uint4*)&wgl[(size_t)bG1*HDIM + bC81];

  for (int k0 = 0; k0 < HDIM; k0 += 32) {
    if (k0) __syncthreads();           // previous compute done reading LDS
    *(uint4*)&ZAh[aHH0*LPAD + aL80] = rA0;
    *(uint4*)&ZAl[aHH1*LPAD + aL81] = rA1;
    *(uint4*)&Bh[bM0*GPAD + bC80] = rBh0;
    *(uint4*)&Bl[bM0*GPAD + bC80] = rBl0;
    *(uint4*)&Bh[bM1*GPAD + bC81] = rBh1;
    *(uint4*)&Bl[bM1*GPAD + bC81] = rBl1;
    __syncthreads();
    if (k0 + 32 < HDIM) {              // prefetch next k-step (hides under compute)
      int kn = k0 + 32;
      rA0 = *(const uint4*)&zth[((size_t)(b*HDIM + kn + aHH0))*LSEQ + l0g + aL80];
      rA1 = *(const uint4*)&ztl[((size_t)(b*HDIM + kn + aHH1))*LSEQ + l0g + aL81];
      rBh0 = *(const uint4*)&wgh[(size_t)bG0*HDIM + kn + bC80];
      rBl0 = *(const uint4*)&wgl[(size_t)bG0*HDIM + kn + bC80];
      rBh1 = *(const uint4*)&wgh[(size_t)bG1*HDIM + kn + bC81];
      rBl1 = *(const uint4*)&wgl[(size_t)bG1*HDIM + kn + bC81];
    }
    const int hbase = 8*(l>>4);
    const int lrow = 16*w + (l&15);
    union { unsigned short s[8]; bfrag8 f; } Uh, Ul;
#pragma unroll
    for (int j = 0; j < 8; ++j) {
      Uh.s[j] = ZAh[(hbase+j)*LPAD + lrow];
      Ul.s[j] = ZAl[(hbase+j)*LPAD + lrow];
    }
    bfrag8 afh = Uh.f, afl = Ul.f;
    const int koff = (l>>4)*8;
#pragma unroll
    for (int ag=0; ag<2; ++ag)
#pragma unroll
      for (int nf=0; nf<4; ++nf) {
        int brow = ag*64 + 16*nf + (l&15);
        bfrag8 bh = *(const bfrag8*)&Bh[brow*GPAD + koff];
        bfrag8 bl = *(const bfrag8*)&Bl[brow*GPAD + koff];
        acc[nf][ag] = __builtin_amdgcn_mfma_f32_16x16x32_bf16(afh, bh, acc[nf][ag], 0,0,0);
        acc[nf][ag] = __builtin_amdgcn_mfma_f32_16x16x32_bf16(afl, bh, acc[nf][ag], 0,0,0);
        acc[nf][ag] = __builtin_amdgcn_mfma_f32_16x16x32_bf16(afh, bl, acc[nf][ag], 0,0,0);
      }
  }
  __syncthreads();
  float* TT = (float*)LB;   // [64 c][68]
#pragma unroll
  for (int nf=0;nf<4;++nf)
#pragma unroll
    for (int r=0;r<4;++r) {
      int m = w*16 + 4*(l>>4) + r;
      int cc2 = 16*nf + (l&15);
      int c = c0 + cc2;
      float av = acc[nf][0][r] + bias[c];
      float gv = acc[nf][1][r] + bias[256+c];
      float val = u[(size_t)(r0+m)*HDIM + c] + av * (1.f/(1.f + expf(-gv)));
      u[(size_t)(r0+m)*HDIM + c] = val;
      TT[cc2*68 + m] = val;
    }
  __syncthreads();
  {
    int cc2 = tid >> 2, mq = (tid & 3)*16;
    size_t ob = ((size_t)(b*HDIM + c0+cc2))*LSEQ + l0g + mq;
#pragma unroll
    for (int q4 = 0; q4 < 16; q4 += 4) {
      float4 v = *(const float4*)&TT[cc2*68 + mq + q4];
      float vv[4] = {v.x,v.y,v.z,v.w};
      unsigned short sh[4], sl[4];
#pragma unroll
      for (int q=0;q<4;++q){ sh[q]=f2bf(vv[q]); sl[q]=f2bf(vv[q]-bf2f(sh[q])); }
      *(unsigned long long*)&uth[ob+q4] = pk4(sh[0],sh[1],sh[2],sh[3]);
      *(unsigned long long*)&utl[ob+q4] = pk4(sl[0],sl[1],sl[2],sl[3]);
    }
  }
}

// ---------------- LayerNorm -> split-bf16 un
__global__ __launch_bounds__(256) void ln_kernel(
    const float* __restrict__ u, const float* __restrict__ g,
    const float* __restrict__ b, unsigned short* __restrict__ unh,
    unsigned short* __restrict__ unl) {
  const int r0 = blockIdx.x * 8;
  const int w = threadIdx.x >> 6;
  const int lane = threadIdx.x & 63;
#pragma unroll
  for (int rr = 0; rr < 2; ++rr) {
    int r = r0 + w*2 + rr;
    float4 v = *(const float4*)&u[(size_t)r*HDIM + lane*4];
    float s = v.x+v.y+v.z+v.w;
    float sq = v.x*v.x + v.y*v.y + v.z*v.z + v.w*v.w;
    s = wave_sum64(s);
    sq = wave_sum64(sq);
    float mu = rdlane(s, 63) * (1.f/256.f);
    float ms = rdlane(sq, 63) * (1.f/256.f);
    float rstd = rsqrtf(ms - mu*mu + 1e-5f);
    float4 gg = *(const float4*)&g[lane*4];
    float4 bb = *(const float4*)&b[lane*4];
    float o[4];
    o[0] = (v.x-mu)*rstd*gg.x + bb.x;
    o[1] = (v.y-mu)*rstd*gg.y + bb.y;
    o[2] = (v.z-mu)*rstd*gg.z + bb.z;
    o[3] = (v.w-mu)*rstd*gg.w + bb.w;
    unsigned short sh[4], sl[4];
#pragma unroll
    for (int q = 0; q < 4; ++q) {
      sh[q] = f2bf(o[q]); sl[q] = f2bf(o[q] - bf2f(sh[q]));
    }
    size_t ob = (size_t)r*HDIM + lane*4;
    *(unsigned long long*)&unh[ob] = pk4(sh[0],sh[1],sh[2],sh[3]);
    *(unsigned long long*)&unl[ob] = pk4(sl[0],sl[1],sl[2],sl[3]);
  }
}

// ---------------- head: 64r x 64c tile, software-pipelined staging
__global__ __launch_bounds__(256) void head_tile(
    const unsigned short* __restrict__ unh, const unsigned short* __restrict__ unl,
    const unsigned short* __restrict__ whh, const unsigned short* __restrict__ whl,
    const float* __restrict__ hb, float* __restrict__ out) {
  __shared__ __align__(16) unsigned short LB[(2*64 + 2*64)*GPAD];
  unsigned short* Ah = LB;
  unsigned short* Al = LB + 64*GPAD;
  unsigned short* Bh = LB + 2*64*GPAD;
  unsigned short* Bl = LB + 3*64*GPAD;
  const int bx = blockIdx.x, by = blockIdx.y;
  const int tid = threadIdx.x, w = tid >> 6, l = tid & 63;
  const int r0 = bx*64, c0 = by*64;
  facc4 acc[4];
#pragma unroll
  for (int nf=0;nf<4;++nf) acc[nf] = (facc4){0.f,0.f,0.f,0.f};

  const int sM = tid >> 2, sC8 = (tid & 3) * 8;
  uint4 rAh, rAl, rBh, rBl;
  rAh = *(const uint4*)&unh[(size_t)(r0+sM)*HDIM + sC8];
  rAl = *(const uint4*)&unl[(size_t)(r0+sM)*HDIM + sC8];
  rBh = *(const uint4*)&whh[(size_t)(c0+sM)*HDIM + sC8];
  rBl = *(const uint4*)&whl[(size_t)(c0+sM)*HDIM + sC8];

  for (int k0 = 0; k0 < HDIM; k0 += 32) {
    if (k0) __syncthreads();
    *(uint4*)&Ah[sM*GPAD + sC8] = rAh;
    *(uint4*)&Al[sM*GPAD + sC8] = rAl;
    *(uint4*)&Bh[sM*GPAD + sC8] = rBh;
    *(uint4*)&Bl[sM*GPAD + sC8] = rBl;
    __syncthreads();
    if (k0 + 32 < HDIM) {
      int kn = k0 + 32;
      rAh = *(const uint4*)&unh[(size_t)(r0+sM)*HDIM + kn + sC8];
      rAl = *(const uint4*)&unl[(size_t)(r0+sM)*HDIM + kn + sC8];
      rBh = *(const uint4*)&whh[(size_t)(c0+sM)*HDIM + kn + sC8];
      rBl = *(const uint4*)&whl[(size_t)(c0+sM)*HDIM + kn + sC8];
    }
    const int koff = (l>>4)*8;
    const int arow = w*16 + (l&15);
    bfrag8 afh = *(const bfrag8*)&Ah[arow*GPAD + koff];
    bfrag8 afl = *(const bfrag8*)&Al[arow*GPAD + koff];
#pragma unroll
    for (int nf=0; nf<4; ++nf) {
      int brow = 16*nf + (l&15);
      bfrag8 bh = *(const bfrag8*)&Bh[brow*GPAD + koff];
      bfrag8 bl = *(const bfrag8*)&Bl[brow*GPAD + koff];
      acc[nf] = __builtin_amdgcn_mfma_f32_16x16x32_bf16(afh, bh, acc[nf], 0,0,0);
      acc[nf] = __builtin_amdgcn_mfma_f32_16x16x32_bf16(afl, bh, acc[nf], 0,0,0);
      acc[nf] = __builtin_amdgcn_mfma_f32_16x16x32_bf16(afh, bl, acc[nf], 0,0,0);
    }
  }
#pragma unroll
  for (int nf=0;nf<4;++nf) {
    int c = c0 + 16*nf + (l&15);
    if (c < OUTC) {
#pragma unroll
      for (int r=0;r<4;++r) {
        int m = w*16 + 4*(l>>4) + r;
        out[(size_t)(r0+m)*OUTC + c] = acc[nf][r] + hb[c];
      }
    }
  }
}

// ---------------- weight prep: transpose + split
__global__ void prep_wglu(const float* __restrict__ w,
    unsigned short* __restrict__ oh, unsigned short* __restrict__ ol) {
  __shared__ float t[32][33];
  int d = blockIdx.z, k0 = blockIdx.y*32, n0 = blockIdx.x*32;
  int tx = threadIdx.x, ty = threadIdx.y;
#pragma unroll
  for (int i = 0; i < 32; i += 8)
    t[ty+i][tx] = w[((size_t)(d*HDIM + k0+ty+i))*512 + n0+tx];
  __syncthreads();
#pragma unroll
  for (int i = 0; i < 32; i += 8) {
    float v = t[tx][ty+i];
    size_t o = ((size_t)(d*512 + n0+ty+i))*HDIM + k0+tx;
    unsigned short hh = f2bf(v);
    oh[o] = hh; ol[o] = f2bf(v - bf2f(hh));
  }
}

__global__ void prep_whead(const float* __restrict__ w,
    unsigned short* __restrict__ oh, unsigned short* __restrict__ ol) {
  __shared__ float t[32][33];
  int k0 = blockIdx.y*32, n0 = blockIdx.x*32;
  int tx = threadIdx.x, ty = threadIdx.y;
#pragma unroll
  for (int i = 0; i < 32; i += 8)
    t[ty+i][tx] = (n0+tx < OUTC) ? w[(size_t)(k0+ty+i)*OUTC + n0+tx] : 0.f;
  __syncthreads();
#pragma unroll
  for (int i = 0; i < 32; i += 8) {
    float v = t[tx][ty+i];
    size_t o = (size_t)(n0+ty+i)*HDIM + k0+tx;
    unsigned short hh = f2bf(v);
    oh[o] = hh; ol[o] = f2bf(v - bf2f(hh));
  }
}

extern "C" void kernel_launch(void* const* d_in, const int* in_sizes, int n_in,
                              void* d_out, int out_size, void* d_ws, size_t ws_size,
                              hipStream_t stream) {
  const float* x       = (const float*)d_in[0];
  const float* proj_w  = (const float*)d_in[1];
  const float* proj_b  = (const float*)d_in[2];
  const float* log_dt  = (const float*)d_in[3];
  const float* lAr     = (const float*)d_in[4];
  const float* Aim     = (const float*)d_in[5];
  const float* Cre     = (const float*)d_in[6];
  const float* Cim     = (const float*)d_in[7];
  const float* Dp      = (const float*)d_in[8];
  const float* out_w   = (const float*)d_in[9];
  const float* out_b   = (const float*)d_in[10];
  const float* ln_g    = (const float*)d_in[11];
  const float* ln_b    = (const float*)d_in[12];
  const float* head_w  = (const float*)d_in[13];
  const float* head_b  = (const float*)d_in[14];
  float* outp = (float*)d_out;

  size_t fixed = (size_t)NROWS*HDIM*4          // u fp32
               + (size_t)NROWS*HDIM*2*4        // uth, utl, zth, ztl
               + (size_t)4*512*HDIM*2*2        // wgh, wgl
               + (size_t)HDIM*HDIM*2*2         // whh, whl
               + (size_t)NDEPTH*4*HN*4         // coef
               + (size_t)2*NDEPTH*HN*16;       // aa, cc double2
  size_t need_small = fixed + (size_t)10*M1*2;
  size_t need_big   = fixed + (size_t)NDEPTH*10*M1*2;
  if (ws_size < need_small) return;
  const bool big = (ws_size >= need_big);

  char* p = (char*)d_ws;
  float* u    = (float*)p;            p += (size_t)NROWS*HDIM*4;
  unsigned short* uth = (unsigned short*)p; p += (size_t)NROWS*HDIM*2;
  unsigned short* utl = (unsigned short*)p; p += (size_t)NROWS*HDIM*2;
  unsigned short* zth = (unsigned short*)p; p += (size_t)NROWS*HDIM*2;
  unsigned short* ztl = (unsigned short*)p; p += (size_t)NROWS*HDIM*2;
  unsigned short* wgh = (unsigned short*)p; p += (size_t)4*512*HDIM*2;
  unsigned short* wgl = (unsigned short*)p; p += (size_t)4*512*HDIM*2;
  unsigned short* whh = (unsigned short*)p; p += (size_t)HDIM*HDIM*2;
  unsigned short* whl = (unsigned short*)p; p += (size_t)HDIM*HDIM*2;
  float* coef = (float*)p;            p += (size_t)NDEPTH*4*HN*4;
  double2* aa = (double2*)p;          p += (size_t)NDEPTH*HN*16;
  double2* cc = (double2*)p;          p += (size_t)NDEPTH*HN*16;
  unsigned short* mats = (unsigned short*)p;   // flex region (1 or 4 layers)
  unsigned short* unh = uth;  // reuse after last layer
  unsigned short* unl = utl;

  coef_kernel<<<NDEPTH*HN/256, 256, 0, stream>>>(log_dt, lAr, Aim, Cre, Cim, aa, cc, coef);
  prep_wglu<<<dim3(16, 8, 4), dim3(32,8), 0, stream>>>(out_w, wgh, wgl);
  prep_whead<<<dim3(8, 8), dim3(32,8), 0, stream>>>(head_w, whh, whl);
  if (big) {
    build_mats<<<dim3(HDIM, NDEPTH, 3), 256, 0, stream>>>(aa, cc, Dp, mats);
  }
  proj_kernel<<<NROWS/8, 256, 0, stream>>>(x, proj_w, proj_b, u, uth, utl);

  for (int d = 0; d < NDEPTH; ++d) {
    if (!big) {
      build_mats<<<dim3(HDIM, 1, 3), 256, 0, stream>>>(
          aa + (size_t)d*HN, cc + (size_t)d*HN, Dp + d*HDIM, mats);
    }
    unsigned short* md = mats + (big ? (size_t)d*10*M1 : 0);
    scan_gemm<<<dim3(HDIM, NBATCH), 256, 0, stream>>>(
        uth, utl, md, coef + (size_t)d*4*HN, zth, ztl);
    glu_tile<<<dim3(NROWS/64, 4), 256, 0, stream>>>(
        zth, ztl, wgh + (size_t)d*512*HDIM, wgl + (size_t)d*512*HDIM,
        out_b + d*512, u, uth, utl);
  }

  ln_kernel<<<NROWS/8, 256, 0, stream>>>(u, ln_g, ln_b, unh, unl);
  head_tile<<<dim3(NROWS/64, 4), 256, 0, stream>>>(unh, unl, whh, whl, head_b, outp);
}